// Round 5
// baseline (402.590 us; speedup 1.0000x reference)
//
#include <hip/hip_runtime.h>
#include <stdint.h>

#define NN 4096
#define NC 7
#define SIG1 0.7310585786300049f
#define PER_C 0.001f

typedef unsigned long long u64;

// ---------------- ws layout ----------------
#define BITS_OFF   0                          // u64 bits[4096][64] = 2MB
#define CBITS_OFF  (2*1024*1024)              // u64 cbits[4096][64] = 2MB (corr bits, compact idx)
#define DEG_OFF    (4*1024*1024)              // int deg[4096]
#define DIAGP_OFF  (DEG_OFF   + NN*4)         // float diagP[4096]
#define CPOS_OFF   (DIAGP_OFF + NN*4)         // int cpos[4096]: compact idx or -1
#define MIDX_OFF   (CPOS_OFF  + NN*4)         // int midx[4096]
#define MLAB_OFF   (MIDX_OFF  + NN*4)         // int mlab[4096]
#define SELFC_OFF  (MLAB_OFF  + NN*4)         // int selfc[4096]: adj[q,q] by compact idx
#define ACC_OFF    (SELFC_OFF + NN*4)
// acc float-word idx: 0..48 T, 49..55 Ncnt(int), 56..59 masks(2 x u64),
//                     60 M(int), 61..76 ce_part[16], 77 done(int)

// Blocks 0..15: CE partials + diagP. Block 16: zero acc, compact scan, cpos,
// Ncnt, M, selfc (adj diagonal).
__global__ void k_prep2(const float* __restrict__ preds, const int* __restrict__ labels,
                        const int* __restrict__ mask, const int* __restrict__ adj,
                        float* __restrict__ diagP,
                        int* __restrict__ midx, int* __restrict__ mlab,
                        int* __restrict__ cpos, int* __restrict__ selfc,
                        float* __restrict__ acc) {
    int t = threadIdx.x;
    if (blockIdx.x == 16) {
        __shared__ int cnts[256];
        __shared__ int sN[NC];
        if (t < 49) acc[t] = 0.f;                 // T
        if (t >= 56 && t < 60) acc[t] = 0.f;      // masks
        if (t == 77) acc[t] = 0.f;                // done counter
        if (t < NC) sN[t] = 0;
        for (int i = t; i < NN; i += 256) { midx[i] = 0; mlab[i] = 0; cpos[i] = -1; }

        int base_n = t * 16;
        int my[16];
        int c = 0;
        #pragma unroll
        for (int k = 0; k < 16; k++) { my[k] = mask[base_n + k]; c += (my[k] != 0); }
        cnts[t] = c;
        __syncthreads();
        for (int s = 1; s < 256; s <<= 1) {
            int v = (t >= s) ? cnts[t - s] : 0;
            __syncthreads();
            cnts[t] += v;
            __syncthreads();
        }
        int pos = cnts[t] - c;  // exclusive prefix
        #pragma unroll
        for (int k = 0; k < 16; k++) {
            if (my[k]) {
                int node = base_n + k;
                int l = labels[node];
                midx[pos] = node;
                mlab[pos] = l;
                cpos[node] = pos;
                atomicAdd(&sN[l], 1);
                pos++;
            }
        }
        __syncthreads();
        int M = cnts[255];
        for (int i = t; i < M; i += 256)
            selfc[i] = (adj[(size_t)midx[i] * (NN + 1)] != 0);
        if (t < NC) ((int*)acc)[49 + t] = sN[t];
        if (t == 255) ((int*)acc)[60] = M;
    } else {
        int p = blockIdx.x * 256 + t;
        int l = labels[p];
        const float* pr = preds + p * NC;
        float x[NC];
        #pragma unroll
        for (int c = 0; c < NC; c++) x[c] = pr[c];
        float mx = x[0];
        #pragma unroll
        for (int c = 1; c < NC; c++) mx = fmaxf(mx, x[c]);
        float s = 0.f;
        #pragma unroll
        for (int c = 0; c < NC; c++) s += __expf(x[c] - mx);
        float lse = mx + logf(s);
        float dp = x[l];
        diagP[p] = dp;

        __shared__ float red[256];
        red[t] = lse - dp;
        __syncthreads();
        for (int st = 128; st > 0; st >>= 1) {
            if (t < st) red[t] += red[t + st];
            __syncthreads();
        }
        if (t == 0) acc[61 + blockIdx.x] = red[0];
    }
}

// Build bitset rows + deg + (for masked rows) the correction-bit row:
// cbits[cpos[r]][w] bit k = adj[r, midx[64w+k]] & ~adj[midx..,midx..].
// One wave per row; the wave holds the full 4096-bit row in registers (myw),
// so cbits comes from __shfl gathers + ballots — no second pass over memory.
__global__ void k_build(const int* __restrict__ adj, u64* __restrict__ bits,
                        int* __restrict__ deg,
                        const int* __restrict__ cpos, const int* __restrict__ midx,
                        const int* __restrict__ selfc, const float* __restrict__ acc,
                        u64* __restrict__ cbits) {
    int row = blockIdx.x * 4 + (threadIdx.x >> 6);
    int lane = threadIdx.x & 63;
    const int* arow = adj + (size_t)row * NN;
    u64 myw = 0ull;
    #pragma unroll 8
    for (int w = 0; w < 64; w++) {
        u64 m = __ballot(arow[w * 64 + lane] != 0);
        if (lane == w) myw = m;
    }
    bits[(size_t)row * 64 + lane] = myw;
    int d = __popcll(myw);
    #pragma unroll
    for (int o = 32; o > 0; o >>= 1) d += __shfl_down(d, o);
    if (lane == 0) deg[row] = d;

    int ci = cpos[row];
    if (ci >= 0) {
        int M = ((const int*)acc)[60];
        for (int w = 0; w * 64 < M && w < 64; w++) {
            int qi = w * 64 + lane;
            int ok = (qi < M) ? 1 : 0;
            int col = ok ? midx[qi] : 0;
            u64 src = __shfl(myw, col >> 6);
            int bit = ok & (int)((src >> (col & 63)) & 1ull) & (ok ? (selfc[qi] ^ 1) : 0);
            u64 word = __ballot(bit != 0);
            if (lane == 0) cbits[(size_t)ci * 64 + w] = word;
        }
    }
}

// Pair kernel over compacted masked nodes. 256 threads (4 waves), 64x64 tile,
// 4x4 per thread; K in 2 halves of 16 x 16B chunks, LDS ~36KB -> 4 blocks/CU
// (16 waves/CU, 4/SIMD). Swizzle sc = lc ^ ((row>>2)&7): core reads <=2-way.
// predsQ stride 65 kills the label-row bank aliasing. cbits kills the per-pair
// LDS bit extraction. Last finished block computes the final scalar (fused
// k_final: done-counter + agent-scope atomic loads).
__launch_bounds__(256, 4)
__global__ void k_pairs(const u64* __restrict__ bits,
                        const float* __restrict__ preds,
                        const int* __restrict__ deg,
                        const float* __restrict__ diagP,
                        const u64* __restrict__ cbits,
                        const int* __restrict__ midx,
                        const int* __restrict__ mlab,
                        float* __restrict__ acc,
                        float* __restrict__ out) {
    __shared__ ulonglong2 lp[64 * 16];
    __shared__ ulonglong2 lq[64 * 16];
    __shared__ float predsQ[NC * 65];
    __shared__ float diagPp[64];
    __shared__ int labP[64], labQ[64], degP[64], sMp[64], sMq[64];
    __shared__ u64 PQw[64];
    __shared__ float T_lds[49];
    __shared__ unsigned int s_m[4];
    __shared__ int is_last;

    int M = ((const int*)acc)[60];
    int tpq = (M + 63) >> 6;
    int nT = tpq * tpq;
    int t = threadIdx.x;
    bool active = ((int)blockIdx.x < nT);

    if (active) {
        int trow = blockIdx.x / tpq;
        int p0 = trow << 6, q0 = ((int)blockIdx.x - trow * tpq) << 6;

        if (t < 49) T_lds[t] = 0.f;
        if (t >= 49 && t < 53) s_m[t - 49] = 0u;
        if (t < 64) {
            int pi = midx[p0 + t], qi = midx[q0 + t];
            sMp[t] = pi; sMq[t] = qi;
            diagPp[t] = diagP[pi];
            degP[t]   = deg[pi];
            labP[t]   = mlab[p0 + t];
            labQ[t]   = mlab[q0 + t];
            PQw[t]    = cbits[(size_t)(p0 + t) * 64 + (q0 >> 6)];
        }
        for (int idx = t; idx < NC * 64; idx += 256) {
            int c = idx >> 6, r = idx & 63;
            predsQ[c * 65 + r] = preds[midx[q0 + r] * NC + c];
        }

        int tx = t & 15, ty = t >> 4;
        int cnt[4][4];
        #pragma unroll
        for (int i = 0; i < 4; i++)
            #pragma unroll
            for (int j = 0; j < 4; j++) cnt[i][j] = 0;

        for (int h = 0; h < 2; h++) {
            __syncthreads();
            #pragma unroll
            for (int i2 = 0; i2 < 4; i2++) {
                int idx = t + 256 * i2;            // 0..1023: 64 rows x 16 chunks
                int row = idx >> 4, lc = idx & 15;
                int sc = lc ^ ((row >> 2) & 7);
                lp[row * 16 + sc] = *(const ulonglong2*)&bits[(size_t)sMp[row] * 64 + 32 * h + 2 * lc];
                lq[row * 16 + sc] = *(const ulonglong2*)&bits[(size_t)sMq[row] * 64 + 32 * h + 2 * lc];
            }
            __syncthreads();

            const ulonglong2* Ap = lp + ty * 64;   // row 4ty+i at chunk base ty*64 + i*16
            const ulonglong2* Bp = lq + tx * 64;
            #pragma unroll 4
            for (int c = 0; c < 16; c++) {
                int sa = c ^ (ty & 7);
                int sb = c ^ (tx & 7);
                ulonglong2 a[4], b[4];
                #pragma unroll
                for (int i = 0; i < 4; i++) a[i] = Ap[i * 16 + sa];
                #pragma unroll
                for (int j = 0; j < 4; j++) b[j] = Bp[j * 16 + sb];
                #pragma unroll
                for (int i = 0; i < 4; i++)
                    #pragma unroll
                    for (int j = 0; j < 4; j++)
                        cnt[i][j] += __popcll(a[i].x & b[j].x) + __popcll(a[i].y & b[j].y);
            }
        }

        u64 lsub = 0ull, linter = 0ull;
        int lqr[4];
        unsigned int pqb[4];
        #pragma unroll
        for (int j = 0; j < 4; j++) lqr[j] = labQ[4 * tx + j];
        #pragma unroll
        for (int i = 0; i < 4; i++) pqb[i] = (unsigned int)((PQw[4 * ty + i] >> (4 * tx)) & 0xfull);

        #pragma unroll
        for (int i = 0; i < 4; i++) {
            int pl = 4 * ty + i;
            if (p0 + pl >= M) continue;
            int lp_ = labP[pl], dgp = degP[pl];
            float dPp = diagPp[pl];
            #pragma unroll
            for (int j = 0; j < 4; j++) {
                int ql = 4 * tx + j;
                if (q0 + ql >= M) continue;
                int inter = cnt[i][j];
                int sub = dgp - inter - (int)((pqb[i] >> j) & 1u);
                int lq_ = lqr[j];
                int bidx = lp_ * 7 + lq_;
                if (sub > 0)   lsub   |= 1ull << bidx;
                if (inter > 0) linter |= 1ull << bidx;
                if (lp_ != lq_) {
                    float arg = (1.f + SIG1 * (float)sub) / (1.f + SIG1 * (float)inter);
                    float v = 1.f / (1.f + __expf(arg));            // 1 - sigmoid(arg)
                    float E = __expf(predsQ[lp_ * 65 + ql] - dPp);  // exp(G - diagP)
                    atomicAdd(&T_lds[bidx], E * v);
                }
            }
        }
        atomicOr(&s_m[0], (unsigned int)(lsub & 0xffffffffull));
        atomicOr(&s_m[1], (unsigned int)(lsub >> 32));
        atomicOr(&s_m[2], (unsigned int)(linter & 0xffffffffull));
        atomicOr(&s_m[3], (unsigned int)(linter >> 32));
        __syncthreads();

        if (t < 49) { float v = T_lds[t]; if (v != 0.f) atomicAdd(&acc[t], v); }
        if (t >= 64 && t < 68) {
            unsigned int m = s_m[t - 64];
            if (m) atomicOr((unsigned int*)(acc + 56) + (t - 64), m);
        }
    }

    // fused finalize: last block to arrive computes the output scalar
    __threadfence();
    if (t == 0) {
        int old = atomicAdd((int*)(acc + 77), 1);
        is_last = (old == (int)gridDim.x - 1);
    }
    __syncthreads();
    if (is_last && t == 0) {
        float ce = 0.f;
        for (int b = 0; b < 16; b++) ce += acc[61 + b];
        ce /= (float)NN;
        u64 msub = __hip_atomic_load((u64*)(acc + 56), __ATOMIC_RELAXED, __HIP_MEMORY_SCOPE_AGENT);
        u64 mint = __hip_atomic_load((u64*)(acc + 58), __ATOMIC_RELAXED, __HIP_MEMORY_SCOPE_AGENT);
        u64 hb = msub & mint;
        const int* Ncnt = (const int*)(acc + 49);
        float invN[NC];
        #pragma unroll
        for (int c = 0; c < NC; c++) { int n = Ncnt[c]; invN[c] = (n > 0) ? 1.f / (float)n : 0.f; }
        float lp_ = 0.f;
        for (int c1 = 0; c1 < NC; c1++)
            for (int c2 = 0; c2 < NC; c2++) {
                int b = c1 * 7 + c2;
                if ((hb >> b) & 1ull) {
                    float tv = __hip_atomic_load(acc + b, __ATOMIC_RELAXED, __HIP_MEMORY_SCOPE_AGENT);
                    lp_ += invN[c1] * invN[c2] * tv;
                }
            }
        out[0] = ce + PER_C * lp_;
    }
}

extern "C" void kernel_launch(void* const* d_in, const int* in_sizes, int n_in,
                              void* d_out, int out_size, void* d_ws, size_t ws_size,
                              hipStream_t stream) {
    const float* preds  = (const float*)d_in[0];
    const int*   labels = (const int*)d_in[1];
    const int*   mask   = (const int*)d_in[2];
    const int*   adj    = (const int*)d_in[3];
    float* out = (float*)d_out;

    char* ws = (char*)d_ws;
    u64*   bits  = (u64*)(ws + BITS_OFF);
    u64*   cbits = (u64*)(ws + CBITS_OFF);
    int*   deg   = (int*)(ws + DEG_OFF);
    float* diagP = (float*)(ws + DIAGP_OFF);
    int*   cpos  = (int*)(ws + CPOS_OFF);
    int*   midx  = (int*)(ws + MIDX_OFF);
    int*   mlab  = (int*)(ws + MLAB_OFF);
    int*   selfc = (int*)(ws + SELFC_OFF);
    float* acc   = (float*)(ws + ACC_OFF);

    k_prep2<<<17, 256, 0, stream>>>(preds, labels, mask, adj, diagP, midx, mlab, cpos, selfc, acc);
    k_build<<<1024, 256, 0, stream>>>(adj, bits, deg, cpos, midx, selfc, acc, cbits);
    k_pairs<<<4096, 256, 0, stream>>>(bits, preds, deg, diagP, cbits, midx, mlab, acc, out);
}

// Round 6
// 201.570 us; speedup vs baseline: 1.9973x; 1.9973x over previous
//
#include <hip/hip_runtime.h>
#include <stdint.h>

#define NN 4096
#define NC 7
#define SIG1 0.7310585786300049f
#define PER_C 0.001f

typedef unsigned long long u64;

// ---------------- ws layout ----------------
#define BITS_OFF   0                          // u64 bits[4096][64] = 2MB
#define CBITS_OFF  (2*1024*1024)              // u64 cbits[4096][64] = 2MB (corr bits, compact idx)
#define DEG_OFF    (4*1024*1024)              // int deg[4096]
#define DIAGP_OFF  (DEG_OFF   + NN*4)         // float diagP[4096]
#define CPOS_OFF   (DIAGP_OFF + NN*4)         // int cpos[4096]: compact idx or -1
#define MIDX_OFF   (CPOS_OFF  + NN*4)         // int midx[4096] (label-sorted masked ids)
#define MLAB_OFF   (MIDX_OFF  + NN*4)         // int mlab[4096]
#define SELFC_OFF  (MLAB_OFF  + NN*4)         // int selfc[4096]: adj[q,q] by compact idx
#define ACC_OFF    (SELFC_OFF + NN*4)
// acc float-word idx: 0..48 T, 49..55 Ncnt(int), 56..59 masks(2 x u64),
//                     60 M(int), 61..76 ce_part[16]

// Blocks 0..15: CE partials + diagP. Block 16: zero acc, LABEL-SORTED compaction
// (counting sort: pair sum is order-independent, stability unneeded), Ncnt, M,
// selfc (adj diagonal).
__global__ void k_prep2(const float* __restrict__ preds, const int* __restrict__ labels,
                        const int* __restrict__ mask, const int* __restrict__ adj,
                        float* __restrict__ diagP,
                        int* __restrict__ midx, int* __restrict__ mlab,
                        int* __restrict__ cpos, int* __restrict__ selfc,
                        float* __restrict__ acc) {
    int t = threadIdx.x;
    if (blockIdx.x == 16) {
        __shared__ int sN[NC];
        __shared__ int cur[NC];
        __shared__ int sM;
        if (t < 49) acc[t] = 0.f;                 // T
        if (t >= 56 && t < 60) acc[t] = 0.f;      // masks
        if (t < NC) sN[t] = 0;
        for (int i = t; i < NN; i += 256) { midx[i] = 0; mlab[i] = 0; cpos[i] = -1; }
        __syncthreads();

        int base_n = t * 16;
        int my[16], lb[16];
        #pragma unroll
        for (int k = 0; k < 16; k++) {
            my[k] = mask[base_n + k];
            lb[k] = labels[base_n + k];
            if (my[k]) atomicAdd(&sN[lb[k]], 1);
        }
        __syncthreads();
        if (t == 0) {
            int run = 0;
            for (int c = 0; c < NC; c++) { cur[c] = run; run += sN[c]; }
            sM = run;
        }
        __syncthreads();
        #pragma unroll
        for (int k = 0; k < 16; k++) {
            if (my[k]) {
                int node = base_n + k;
                int l = lb[k];
                int pos = atomicAdd(&cur[l], 1);
                midx[pos] = node;
                mlab[pos] = l;
                cpos[node] = pos;
            }
        }
        __syncthreads();
        int M = sM;
        for (int i = t; i < M; i += 256)
            selfc[i] = (adj[(size_t)midx[i] * (NN + 1)] != 0);
        if (t < NC) ((int*)acc)[49 + t] = sN[t];
        if (t == 0) ((int*)acc)[60] = M;
    } else {
        int p = blockIdx.x * 256 + t;
        int l = labels[p];
        const float* pr = preds + p * NC;
        float x[NC];
        #pragma unroll
        for (int c = 0; c < NC; c++) x[c] = pr[c];
        float mx = x[0];
        #pragma unroll
        for (int c = 1; c < NC; c++) mx = fmaxf(mx, x[c]);
        float s = 0.f;
        #pragma unroll
        for (int c = 0; c < NC; c++) s += __expf(x[c] - mx);
        float lse = mx + logf(s);
        float dp = x[l];
        diagP[p] = dp;

        __shared__ float red[256];
        red[t] = lse - dp;
        __syncthreads();
        for (int st = 128; st > 0; st >>= 1) {
            if (t < st) red[t] += red[t + st];
            __syncthreads();
        }
        if (t == 0) acc[61 + blockIdx.x] = red[0];
    }
}

// Build bitset rows + deg + (for masked rows) the correction-bit row:
// cbits[cpos[r]][w] bit k = adj[r, midx[64w+k]] & ~adj[midx..,midx..].
// One wave per row; the wave holds the full 4096-bit row in registers (myw),
// so cbits comes from __shfl gathers + ballots — no second pass over memory.
__global__ void k_build(const int* __restrict__ adj, u64* __restrict__ bits,
                        int* __restrict__ deg,
                        const int* __restrict__ cpos, const int* __restrict__ midx,
                        const int* __restrict__ selfc, const float* __restrict__ acc,
                        u64* __restrict__ cbits) {
    int row = blockIdx.x * 4 + (threadIdx.x >> 6);
    int lane = threadIdx.x & 63;
    const int* arow = adj + (size_t)row * NN;
    u64 myw = 0ull;
    #pragma unroll 8
    for (int w = 0; w < 64; w++) {
        u64 m = __ballot(arow[w * 64 + lane] != 0);
        if (lane == w) myw = m;
    }
    bits[(size_t)row * 64 + lane] = myw;
    int d = __popcll(myw);
    #pragma unroll
    for (int o = 32; o > 0; o >>= 1) d += __shfl_down(d, o);
    if (lane == 0) deg[row] = d;

    int ci = cpos[row];
    if (ci >= 0) {
        int M = ((const int*)acc)[60];
        for (int w = 0; w * 64 < M && w < 64; w++) {
            int qi = w * 64 + lane;
            int ok = (qi < M) ? 1 : 0;
            int col = ok ? midx[qi] : 0;
            u64 src = __shfl(myw, col >> 6);
            int bit = ok & (int)((src >> (col & 63)) & 1ull) & (ok ? (selfc[qi] ^ 1) : 0);
            u64 word = __ballot(bit != 0);
            if (lane == 0) cbits[(size_t)ci * 64 + w] = word;
        }
    }
}

// Pair kernel over label-sorted compacted masked nodes. 256 threads (4 waves),
// 64x64 tile, 4x4/thread; K in 2 halves of 16 x 16B chunks, LDS ~36KB ->
// 4 blocks/CU. Same-label tiles skipped (contribute only to diagonal hb bits,
// which gate T[c,c]==0). NO device fences here: the R5 __threadfence emitted
// a per-XCD L2 invalidate (multi-XCD agent fence) and evicted the bits
// working set -> 4x latency regression. Finalize is a separate kernel.
__launch_bounds__(256, 4)
__global__ void k_pairs(const u64* __restrict__ bits,
                        const float* __restrict__ preds,
                        const int* __restrict__ deg,
                        const float* __restrict__ diagP,
                        const u64* __restrict__ cbits,
                        const int* __restrict__ midx,
                        const int* __restrict__ mlab,
                        float* __restrict__ acc) {
    __shared__ ulonglong2 lp[64 * 16];
    __shared__ ulonglong2 lq[64 * 16];
    __shared__ float predsQ[NC * 65];   // stride 65: decorrelate banks across label rows
    __shared__ float diagPp[64];
    __shared__ int labP[64], labQ[64], degP[64], sMp[64], sMq[64];
    __shared__ u64 PQw[64];
    __shared__ float T_lds[49];
    __shared__ unsigned int s_m[4];

    int M = ((const int*)acc)[60];
    int p0 = blockIdx.y * 64, q0 = blockIdx.x * 64;
    if (p0 >= M || q0 >= M) return;

    int t = threadIdx.x;
    if (t < 49) T_lds[t] = 0.f;
    if (t >= 49 && t < 53) s_m[t - 49] = 0u;
    if (t < 64) {
        labP[t] = mlab[p0 + t];
        labQ[t] = mlab[q0 + t];
    }
    __syncthreads();
    // label-sorted => endpoint check detects single-label tiles; same-label
    // pairs contribute nothing observable -> skip whole tile.
    if (labP[0] == labP[63] && labQ[0] == labQ[63] && labP[0] == labQ[63]) return;

    if (t < 64) {
        int pi = midx[p0 + t], qi = midx[q0 + t];
        sMp[t] = pi; sMq[t] = qi;
        diagPp[t] = diagP[pi];
        degP[t]   = deg[pi];
        PQw[t]    = cbits[(size_t)(p0 + t) * 64 + (q0 >> 6)];
    }
    for (int idx = t; idx < NC * 64; idx += 256) {
        int c = idx >> 6, r = idx & 63;
        predsQ[c * 65 + r] = preds[midx[q0 + r] * NC + c];
    }

    int tx = t & 15, ty = t >> 4;
    int cnt[4][4];
    #pragma unroll
    for (int i = 0; i < 4; i++)
        #pragma unroll
        for (int j = 0; j < 4; j++) cnt[i][j] = 0;

    for (int h = 0; h < 2; h++) {
        __syncthreads();
        #pragma unroll
        for (int i2 = 0; i2 < 4; i2++) {
            int idx = t + 256 * i2;            // 0..1023: 64 rows x 16 chunks
            int row = idx >> 4, lc = idx & 15;
            int sc = lc ^ ((row >> 2) & 7);
            lp[row * 16 + sc] = *(const ulonglong2*)&bits[(size_t)sMp[row] * 64 + 32 * h + 2 * lc];
            lq[row * 16 + sc] = *(const ulonglong2*)&bits[(size_t)sMq[row] * 64 + 32 * h + 2 * lc];
        }
        __syncthreads();

        const ulonglong2* Ap = lp + ty * 64;   // row 4ty+i at chunk base ty*64 + i*16
        const ulonglong2* Bp = lq + tx * 64;
        #pragma unroll 4
        for (int c = 0; c < 16; c++) {
            int sa = c ^ (ty & 7);
            int sb = c ^ (tx & 7);
            ulonglong2 a[4], b[4];
            #pragma unroll
            for (int i = 0; i < 4; i++) a[i] = Ap[i * 16 + sa];
            #pragma unroll
            for (int j = 0; j < 4; j++) b[j] = Bp[j * 16 + sb];
            #pragma unroll
            for (int i = 0; i < 4; i++)
                #pragma unroll
                for (int j = 0; j < 4; j++)
                    cnt[i][j] += __popcll(a[i].x & b[j].x) + __popcll(a[i].y & b[j].y);
        }
    }

    u64 lsub = 0ull, linter = 0ull;
    int lqr[4];
    unsigned int pqb[4];
    #pragma unroll
    for (int j = 0; j < 4; j++) lqr[j] = labQ[4 * tx + j];
    #pragma unroll
    for (int i = 0; i < 4; i++) pqb[i] = (unsigned int)((PQw[4 * ty + i] >> (4 * tx)) & 0xfull);

    #pragma unroll
    for (int i = 0; i < 4; i++) {
        int pl = 4 * ty + i;
        if (p0 + pl >= M) continue;
        int lp_ = labP[pl], dgp = degP[pl];
        float dPp = diagPp[pl];
        #pragma unroll
        for (int j = 0; j < 4; j++) {
            int ql = 4 * tx + j;
            if (q0 + ql >= M) continue;
            int inter = cnt[i][j];
            int sub = dgp - inter - (int)((pqb[i] >> j) & 1u);
            int lq_ = lqr[j];
            int bidx = lp_ * 7 + lq_;
            if (sub > 0)   lsub   |= 1ull << bidx;
            if (inter > 0) linter |= 1ull << bidx;
            if (lp_ != lq_) {
                float arg = (1.f + SIG1 * (float)sub) / (1.f + SIG1 * (float)inter);
                float v = 1.f / (1.f + __expf(arg));            // 1 - sigmoid(arg)
                float E = __expf(predsQ[lp_ * 65 + ql] - dPp);  // exp(G - diagP)
                atomicAdd(&T_lds[bidx], E * v);
            }
        }
    }
    atomicOr(&s_m[0], (unsigned int)(lsub & 0xffffffffull));
    atomicOr(&s_m[1], (unsigned int)(lsub >> 32));
    atomicOr(&s_m[2], (unsigned int)(linter & 0xffffffffull));
    atomicOr(&s_m[3], (unsigned int)(linter >> 32));
    __syncthreads();

    if (t < 49) { float v = T_lds[t]; if (v != 0.f) atomicAdd(&acc[t], v); }
    if (t >= 64 && t < 68) {
        unsigned int m = s_m[t - 64];
        if (m) atomicOr((unsigned int*)(acc + 56) + (t - 64), m);
    }
}

__global__ void k_final(const float* __restrict__ acc, float* __restrict__ out) {
    if (threadIdx.x == 0 && blockIdx.x == 0) {
        const float* T = acc;
        const int* Ncnt = (const int*)(acc + 49);
        const u64* m = (const u64*)(acc + 56);
        float ce = 0.f;
        for (int b = 0; b < 16; b++) ce += acc[61 + b];
        ce /= (float)NN;
        u64 hb = m[0] & m[1];
        float invN[NC];
        #pragma unroll
        for (int c = 0; c < NC; c++) { int n = Ncnt[c]; invN[c] = (n > 0) ? 1.f / (float)n : 0.f; }
        float lp = 0.f;
        for (int c1 = 0; c1 < NC; c1++)
            for (int c2 = 0; c2 < NC; c2++) {
                int b = c1 * 7 + c2;
                if ((hb >> b) & 1ull) lp += invN[c1] * invN[c2] * T[b];
            }
        out[0] = ce + PER_C * lp;
    }
}

extern "C" void kernel_launch(void* const* d_in, const int* in_sizes, int n_in,
                              void* d_out, int out_size, void* d_ws, size_t ws_size,
                              hipStream_t stream) {
    const float* preds  = (const float*)d_in[0];
    const int*   labels = (const int*)d_in[1];
    const int*   mask   = (const int*)d_in[2];
    const int*   adj    = (const int*)d_in[3];
    float* out = (float*)d_out;

    char* ws = (char*)d_ws;
    u64*   bits  = (u64*)(ws + BITS_OFF);
    u64*   cbits = (u64*)(ws + CBITS_OFF);
    int*   deg   = (int*)(ws + DEG_OFF);
    float* diagP = (float*)(ws + DIAGP_OFF);
    int*   cpos  = (int*)(ws + CPOS_OFF);
    int*   midx  = (int*)(ws + MIDX_OFF);
    int*   mlab  = (int*)(ws + MLAB_OFF);
    int*   selfc = (int*)(ws + SELFC_OFF);
    float* acc   = (float*)(ws + ACC_OFF);

    k_prep2<<<17, 256, 0, stream>>>(preds, labels, mask, adj, diagP, midx, mlab, cpos, selfc, acc);
    k_build<<<1024, 256, 0, stream>>>(adj, bits, deg, cpos, midx, selfc, acc, cbits);
    dim3 grid(64, 64);
    k_pairs<<<grid, 256, 0, stream>>>(bits, preds, deg, diagP, cbits, midx, mlab, acc);
    k_final<<<1, 64, 0, stream>>>(acc, out);
}

// Round 8
// 197.273 us; speedup vs baseline: 2.0408x; 1.0218x over previous
//
#include <hip/hip_runtime.h>
#include <stdint.h>

#define NN 4096
#define NC 7
#define SIG1 0.7310585786300049f
#define PER_C 0.001f

typedef unsigned long long u64;

// ---------------- ws layout ----------------
#define BITS_OFF   0                          // u64 bits[4096][64] = 2MB
#define DEG_OFF    (2*1024*1024)              // int deg[4096]
#define DIAGP_OFF  (DEG_OFF   + NN*4)         // float diagP[4096]
#define SELFQ_OFF  (DIAGP_OFF + NN*4)         // int selfq[4096] = adj[r,r]
#define MIDX_OFF   (SELFQ_OFF + NN*4)         // int midx[4096] (label-sorted masked ids)
#define MLAB_OFF   (MIDX_OFF  + NN*4)         // int mlab[4096]
#define ACC_OFF    (MLAB_OFF  + NN*4)
// acc float-word idx: 0..48 T, 49..55 Ncnt(int), 56..59 masks(2 x u64),
//                     60 M(int), 61..76 ce_part[16]

// Fused prologue: blocks 0..1023 build bits/deg/selfq (1 wave per adj row);
// blocks 1024..1039 CE partials + diagP; block 1040 zero acc + label-sorted
// compaction. All parts independent (no cross-block reads inside this launch).
__global__ void k_pre(const float* __restrict__ preds, const int* __restrict__ labels,
                      const int* __restrict__ mask, const int* __restrict__ adj,
                      u64* __restrict__ bits, int* __restrict__ deg,
                      int* __restrict__ selfq, float* __restrict__ diagP,
                      int* __restrict__ midx, int* __restrict__ mlab,
                      float* __restrict__ acc) {
    int t = threadIdx.x;
    int bid = blockIdx.x;
    if (bid < 1024) {
        int row = bid * 4 + (t >> 6);
        int lane = t & 63;
        const int* arow = adj + (size_t)row * NN;
        u64 myw = 0ull;
        #pragma unroll 8
        for (int w = 0; w < 64; w++) {
            u64 m = __ballot(arow[w * 64 + lane] != 0);
            if (lane == w) myw = m;
        }
        bits[(size_t)row * 64 + lane] = myw;
        int d = __popcll(myw);
        #pragma unroll
        for (int o = 32; o > 0; o >>= 1) d += __shfl_down(d, o);
        if (lane == 0) deg[row] = d;
        if (lane == (row >> 6)) selfq[row] = (int)((myw >> (row & 63)) & 1ull);
    } else if (bid < 1040) {
        int p = (bid - 1024) * 256 + t;
        int l = labels[p];
        const float* pr = preds + p * NC;
        float x[NC];
        #pragma unroll
        for (int c = 0; c < NC; c++) x[c] = pr[c];
        float mx = x[0];
        #pragma unroll
        for (int c = 1; c < NC; c++) mx = fmaxf(mx, x[c]);
        float s = 0.f;
        #pragma unroll
        for (int c = 0; c < NC; c++) s += __expf(x[c] - mx);
        float lse = mx + logf(s);
        float dp = x[l];
        diagP[p] = dp;

        __shared__ float red[256];
        red[t] = lse - dp;
        __syncthreads();
        for (int st = 128; st > 0; st >>= 1) {
            if (t < st) red[t] += red[t + st];
            __syncthreads();
        }
        if (t == 0) acc[61 + (bid - 1024)] = red[0];
    } else {
        __shared__ int sN[NC];
        __shared__ int cur[NC];
        __shared__ int sM;
        if (t < 49) acc[t] = 0.f;                 // T
        if (t >= 56 && t < 60) acc[t] = 0.f;      // masks
        if (t < NC) sN[t] = 0;
        for (int i = t; i < NN; i += 256) { midx[i] = 0; mlab[i] = 0; }
        __syncthreads();

        int base_n = t * 16;
        int my[16], lb[16];
        #pragma unroll
        for (int k = 0; k < 16; k++) {
            my[k] = mask[base_n + k];
            lb[k] = labels[base_n + k];
            if (my[k]) atomicAdd(&sN[lb[k]], 1);
        }
        __syncthreads();
        if (t == 0) {
            int run = 0;
            for (int c = 0; c < NC; c++) { cur[c] = run; run += sN[c]; }
            sM = run;
        }
        __syncthreads();
        #pragma unroll
        for (int k = 0; k < 16; k++) {
            if (my[k]) {
                int node = base_n + k;
                int l = lb[k];
                int pos = atomicAdd(&cur[l], 1);
                midx[pos] = node;
                mlab[pos] = l;
            }
        }
        __syncthreads();
        if (t < NC) ((int*)acc)[49 + t] = sN[t];
        if (t == 0) ((int*)acc)[60] = sM;
    }
}

// Pair kernel, UPPER-TRIANGLE tiles only (adj symmetric => inter and adj[p,q]
// symmetric): each off-diagonal tile emits BOTH orientations in the epilogue.
// Popcount core + staging halve; epilogue total unchanged. 256 threads,
// 64x64 tile, 4x4/thread, K in 2 halves, in-LDS bit extraction (lp only;
// self-bits from LDS int arrays). Label-sorted => single-label tiles skipped.
__launch_bounds__(256, 4)
__global__ void k_pairs(const u64* __restrict__ bits,
                        const float* __restrict__ preds,
                        const int* __restrict__ deg,
                        const float* __restrict__ diagP,
                        const int* __restrict__ selfq,
                        const int* __restrict__ midx,
                        const int* __restrict__ mlab,
                        float* __restrict__ acc) {
    __shared__ ulonglong2 lp[64 * 16];
    __shared__ ulonglong2 lq[64 * 16];
    __shared__ float predsQ[NC * 65];   // [c][r] stride 65: conflict-free E reads
    __shared__ float predsP[NC * 65];
    __shared__ float diagPp[64], diagPq[64];
    __shared__ int labP[64], labQ[64], degP[64], degQ[64], selfP[64], selfQ[64];
    __shared__ int sMp[64], sMq[64];
    __shared__ float T_lds[49];
    __shared__ unsigned int s_m[4];

    if (blockIdx.x < blockIdx.y) return;   // upper triangle only (q0 >= p0)
    int M = ((const int*)acc)[60];
    int p0 = blockIdx.y * 64, q0 = blockIdx.x * 64;
    if (p0 >= M || q0 >= M) return;
    bool dual = (q0 != p0);

    int t = threadIdx.x;
    if (t < 64) {
        labP[t] = mlab[p0 + t];
        labQ[t] = mlab[q0 + t];
    }
    __syncthreads();
    // all-one-label tile (both axes, same class): no observable contribution
    if (labP[0] == labP[63] && labQ[0] == labQ[63] && labP[0] == labQ[0]) return;

    if (t < 49) T_lds[t] = 0.f;
    if (t >= 49 && t < 53) s_m[t - 49] = 0u;
    if (t < 64) {
        int pi = midx[p0 + t], qi = midx[q0 + t];
        sMp[t] = pi; sMq[t] = qi;
        diagPp[t] = diagP[pi];
        diagPq[t] = diagP[qi];
        degP[t]   = deg[pi];
        degQ[t]   = deg[qi];
        selfP[t]  = selfq[pi];
        selfQ[t]  = selfq[qi];
    }
    for (int idx = t; idx < NC * 64; idx += 256) {
        int c = idx >> 6, r = idx & 63;
        predsQ[c * 65 + r] = preds[midx[q0 + r] * NC + c];
        predsP[c * 65 + r] = preds[midx[p0 + r] * NC + c];
    }

    int tx = t & 15, ty = t >> 4;
    int cnt[4][4];
    #pragma unroll
    for (int i = 0; i < 4; i++)
        #pragma unroll
        for (int j = 0; j < 4; j++) cnt[i][j] = 0;
    unsigned int pqbits = 0;   // bit (i*4+j) = adj[p_i, q_j] (== adj[q_j, p_i])

    for (int h = 0; h < 2; h++) {
        __syncthreads();
        #pragma unroll
        for (int i2 = 0; i2 < 4; i2++) {
            int idx = t + 256 * i2;            // 0..1023: 64 rows x 16 chunks
            int r2 = idx >> 4, lc = idx & 15;
            int sc = lc ^ ((r2 >> 2) & 7);
            lp[r2 * 16 + sc] = *(const ulonglong2*)&bits[(size_t)sMp[r2] * 64 + 32 * h + 2 * lc];
            lq[r2 * 16 + sc] = *(const ulonglong2*)&bits[(size_t)sMq[r2] * 64 + 32 * h + 2 * lc];
        }
        __syncthreads();

        const ulonglong2* Ap = lp + ty * 64;   // row 4ty+i chunk base = ty*64 + i*16
        const ulonglong2* Bp = lq + tx * 64;
        #pragma unroll 4
        for (int c = 0; c < 16; c++) {
            int sa = c ^ (ty & 7);
            int sb = c ^ (tx & 7);
            ulonglong2 a[4], b[4];
            #pragma unroll
            for (int i = 0; i < 4; i++) a[i] = Ap[i * 16 + sa];
            #pragma unroll
            for (int j = 0; j < 4; j++) b[j] = Bp[j * 16 + sb];
            #pragma unroll
            for (int i = 0; i < 4; i++)
                #pragma unroll
                for (int j = 0; j < 4; j++)
                    cnt[i][j] += __popcll(a[i].x & b[j].x) + __popcll(a[i].y & b[j].y);
        }

        // extract adj[p,q] bits whose q-column chunk lives in this half (lp only)
        #pragma unroll
        for (int j = 0; j < 4; j++) {
            int qorig = sMq[4 * tx + j];
            int qc = qorig >> 7;               // global 16B chunk 0..31
            if ((qc >> 4) == h) {
                int lc = qc & 15;
                int qh = (qorig >> 6) & 1;
                int sh = qorig & 63;
                #pragma unroll
                for (int i = 0; i < 4; i++) {
                    ulonglong2 cp = lp[(4 * ty + i) * 16 + (lc ^ (ty & 7))];
                    u64 w = qh ? cp.y : cp.x;
                    pqbits |= ((unsigned int)((w >> sh) & 1ull)) << (i * 4 + j);
                }
            }
        }
    }

    u64 lsub = 0ull, linter = 0ull;
    #pragma unroll
    for (int i = 0; i < 4; i++) {
        int pl = 4 * ty + i;
        if (p0 + pl >= M) continue;
        int lp_ = labP[pl], dgp = degP[pl], sfp = selfP[pl];
        float dPp = diagPp[pl];
        #pragma unroll
        for (int j = 0; j < 4; j++) {
            int ql = 4 * tx + j;
            if (q0 + ql >= M) continue;
            int inter = cnt[i][j];
            int bit = (int)((pqbits >> (i * 4 + j)) & 1u);
            int lq_ = labQ[ql];
            // orientation (p,q)
            {
                int sub = dgp - inter - (bit & (selfQ[ql] ^ 1));
                int bidx = lp_ * 7 + lq_;
                if (sub > 0)   lsub   |= 1ull << bidx;
                if (inter > 0) linter |= 1ull << bidx;
                if (lp_ != lq_) {
                    float arg = (1.f + SIG1 * (float)sub) / (1.f + SIG1 * (float)inter);
                    float v = 1.f / (1.f + __expf(arg));            // 1 - sigmoid(arg)
                    float E = __expf(predsQ[lp_ * 65 + ql] - dPp);  // exp(preds[q,l_p]-diagP[p])
                    atomicAdd(&T_lds[bidx], E * v);
                }
            }
            // orientation (q,p) — only for off-diagonal tiles
            if (dual) {
                int sub = degQ[ql] - inter - (bit & (sfp ^ 1));
                int bidx = lq_ * 7 + lp_;
                if (sub > 0)   lsub   |= 1ull << bidx;
                if (inter > 0) linter |= 1ull << bidx;
                if (lp_ != lq_) {
                    float arg = (1.f + SIG1 * (float)sub) / (1.f + SIG1 * (float)inter);
                    float v = 1.f / (1.f + __expf(arg));
                    float E = __expf(predsP[lq_ * 65 + pl] - diagPq[ql]);  // exp(preds[p,l_q]-diagP[q])
                    atomicAdd(&T_lds[bidx], E * v);
                }
            }
        }
    }
    atomicOr(&s_m[0], (unsigned int)(lsub & 0xffffffffull));
    atomicOr(&s_m[1], (unsigned int)(lsub >> 32));
    atomicOr(&s_m[2], (unsigned int)(linter & 0xffffffffull));
    atomicOr(&s_m[3], (unsigned int)(linter >> 32));
    __syncthreads();

    if (t < 49) { float v = T_lds[t]; if (v != 0.f) atomicAdd(&acc[t], v); }
    if (t >= 64 && t < 68) {
        unsigned int m = s_m[t - 64];
        if (m) atomicOr((unsigned int*)(acc + 56) + (t - 64), m);
    }
}

__global__ void k_final(const float* __restrict__ acc, float* __restrict__ out) {
    if (threadIdx.x == 0 && blockIdx.x == 0) {
        const float* T = acc;
        const int* Ncnt = (const int*)(acc + 49);
        const u64* m = (const u64*)(acc + 56);
        float ce = 0.f;
        for (int b = 0; b < 16; b++) ce += acc[61 + b];
        ce /= (float)NN;
        u64 hb = m[0] & m[1];
        float invN[NC];
        #pragma unroll
        for (int c = 0; c < NC; c++) { int n = Ncnt[c]; invN[c] = (n > 0) ? 1.f / (float)n : 0.f; }
        float lp = 0.f;
        for (int c1 = 0; c1 < NC; c1++)
            for (int c2 = 0; c2 < NC; c2++) {
                int b = c1 * 7 + c2;
                if ((hb >> b) & 1ull) lp += invN[c1] * invN[c2] * T[b];
            }
        out[0] = ce + PER_C * lp;
    }
}

extern "C" void kernel_launch(void* const* d_in, const int* in_sizes, int n_in,
                              void* d_out, int out_size, void* d_ws, size_t ws_size,
                              hipStream_t stream) {
    const float* preds  = (const float*)d_in[0];
    const int*   labels = (const int*)d_in[1];
    const int*   mask   = (const int*)d_in[2];
    const int*   adj    = (const int*)d_in[3];
    float* out = (float*)d_out;

    char* ws = (char*)d_ws;
    u64*   bits  = (u64*)(ws + BITS_OFF);
    int*   deg   = (int*)(ws + DEG_OFF);
    float* diagP = (float*)(ws + DIAGP_OFF);
    int*   selfq = (int*)(ws + SELFQ_OFF);
    int*   midx  = (int*)(ws + MIDX_OFF);
    int*   mlab  = (int*)(ws + MLAB_OFF);
    float* acc   = (float*)(ws + ACC_OFF);

    k_pre<<<1041, 256, 0, stream>>>(preds, labels, mask, adj, bits, deg, selfq, diagP, midx, mlab, acc);
    dim3 grid(64, 64);
    k_pairs<<<grid, 256, 0, stream>>>(bits, preds, deg, diagP, selfq, midx, mlab, acc);
    k_final<<<1, 64, 0, stream>>>(acc, out);
}